// Round 17
// baseline (149.977 us; speedup 1.0000x reference)
//
#include <hip/hip_runtime.h>

// Problem dims (fixed by setup_inputs)
constexpr int Bb = 4, Cc = 128, Nn = 4096, Kk = 32, Ns = 16384;
constexpr int ROWS = Bb * Nn;   // 16384 (b*n) rows
constexpr int NK = Nn * Kk;     // 131072 floats per channel slab
constexpr int NPART = 256;      // stats-partial sets (= row-tiles)
constexpr int QOFF = NPART * 128;
constexpr int CAP = 32;         // per-segment list capacity (Poisson(8); exact fallback)
constexpr float EPS = 1e-5f;

typedef __attribute__((ext_vector_type(8))) short short8;
typedef __attribute__((ext_vector_type(4))) float f32x4;

__device__ __forceinline__ unsigned short f2bf(float f) {   // RNE f32->bf16
    unsigned int u = __float_as_uint(f);
    unsigned int r = u + 0x7FFFu + ((u >> 16) & 1u);
    return (unsigned short)(r >> 16);
}

// ---- workspace layout (bytes) ----
constexpr size_t OFF_GX   = 0;                          // 8 MB group-max (row,ch)
constexpr size_t SZ_GX    = (size_t)ROWS * Cc * 4;
constexpr size_t OFF_GDIL = OFF_GX + SZ_GX;             // 8 MB gathered dilated (row,ch)
constexpr size_t OFF_H1   = OFF_GDIL + SZ_GX;
constexpr size_t OFF_H2   = OFF_H1 + SZ_GX;
constexpr size_t SZ_PART  = (size_t)NPART * 128 * 2 * 4;
constexpr size_t OFF_P1   = OFF_H2 + SZ_GX;
constexpr size_t OFF_P2   = OFF_P1 + SZ_PART;
constexpr size_t OFF_FLAG = OFF_P2 + SZ_PART;           // 256 KB verified flags
constexpr size_t OFF_CNT  = OFF_FLAG + (size_t)Bb * Ns * 4;  // 256 KB per-seg counters
constexpr size_t OFF_LIST = OFF_CNT + (size_t)Bb * Ns * 4;   // 8 MB per-seg entry lists
constexpr size_t OFF_VAL  = OFF_LIST + (size_t)Bb * Ns * CAP * 4; // 256 MB sparse (b,n,k)->128ch

// ---- prep: verified flags + zero counters (no 32MB seg buffer anymore) ----
// flags[bb*Ns+fi] = i (claiming gather-row). Garbage entry j validates only if
// fps[j]==fi with j in batch bb -- which itself proves fi is in the set.
__global__ __launch_bounds__(256) void k_prep(const int* __restrict__ fps,
                                              int* __restrict__ flags,
                                              unsigned int* __restrict__ cnt) {
    int t = blockIdx.x * 256 + threadIdx.x;     // 0 .. 65535
    cnt[t] = 0u;
    if (t < ROWS) {
        int bb = t >> 12;
        flags[bb * Ns + fps[t]] = t;
    }
}

// ---- scatter: local max over k + flagged-vector dump (NO atomics on values) ----
// grid (4096, 4), 256 threads. Block = one (b, n): 128 channels x 32 k.
// Setup: flagged k's get a list slot via tiny atomicAdd on cnt[seg] (CAP'd;
//        overflow entries dropped from list -> k_gather's exact fallback).
// Phase 1: coalesced x loads, 3-shuffle max; park flagged k-columns in LDS.
// Phase 2: per flagged k, 128 lanes plain-store the 128-ch vector to
//          val[(b,n,k)] (512B contiguous) -- replaces 7.4M L2 atomic RMWs.
__global__ __launch_bounds__(256) void k_scatter(
        const float* __restrict__ x, const int* __restrict__ gidx,
        const int* __restrict__ flags, const int* __restrict__ fps,
        unsigned int* __restrict__ cnt, int* __restrict__ list,
        float* __restrict__ gx, float* __restrict__ val) {
    int nn = blockIdx.x, bb = blockIdx.y;
    int t = threadIdx.x;
    __shared__ float tile[128][33];
    __shared__ float gbuf[128];
    __shared__ int klist[32];
    __shared__ int nflag;
    __shared__ unsigned int fmask;

    if (t == 0) { nflag = 0; fmask = 0u; }
    __syncthreads();
    if (t < 32) {
        int idxv = gidx[((bb * Nn + nn) << 5) + t];
        int fl = flags[bb * Ns + idxv];
        int j = fl & 16383;
        if (((j >> 12) == bb) && (fps[j] == idxv)) {
            int pos = atomicAdd(&nflag, 1);
            klist[pos] = t;
            atomicOr(&fmask, 1u << t);
            unsigned int slot = atomicAdd(&cnt[bb * Ns + idxv], 1u);
            if (slot < (unsigned)CAP)
                list[((size_t)bb * Ns + idxv) * CAP + slot] = (nn << 5) | t;
        }
    }

    int k4 = (t & 7) * 4;
    int cq = t >> 3;                    // 0..31
    const float* xb = x + (size_t)bb * Cc * NK + (size_t)nn * Kk;
    float4 v[4];
    #pragma unroll
    for (int p = 0; p < 4; p++)
        v[p] = *(const float4*)(xb + (size_t)(cq + p * 32) * NK + k4);

    __syncthreads();                    // fmask/klist ready
    unsigned int mask = fmask;
    bool f0 = (mask >> (k4 + 0)) & 1, f1 = (mask >> (k4 + 1)) & 1;
    bool f2 = (mask >> (k4 + 2)) & 1, f3 = (mask >> (k4 + 3)) & 1;

    #pragma unroll
    for (int p = 0; p < 4; p++) {
        int ch = cq + p * 32;
        float4 w = v[p];
        float m = fmaxf(fmaxf(w.x, w.y), fmaxf(w.z, w.w));
        m = fmaxf(m, __shfl_xor(m, 1, 64));
        m = fmaxf(m, __shfl_xor(m, 2, 64));
        m = fmaxf(m, __shfl_xor(m, 4, 64));
        if ((t & 7) == 0) gbuf[ch] = m;
        if (f0) tile[ch][k4 + 0] = w.x;
        if (f1) tile[ch][k4 + 1] = w.y;
        if (f2) tile[ch][k4 + 2] = w.z;
        if (f3) tile[ch][k4 + 3] = w.w;
    }
    __syncthreads();

    if (t < 128) gx[((size_t)(bb * Nn + nn)) * 128 + t] = gbuf[t];

    int nf = nflag;
    int ch = t & 127, rep = t >> 7;     // two half-blocks process 2 k's/iter
    for (int it = rep; it < nf; it += 2) {
        int k = klist[it];
        val[((size_t)bb * NK + (nn << 5) + k) * 128 + ch] = tile[ch][k];
    }
}

// ---- gather-merge: per gather-row, max its segment's listed vectors + 0 ----
// grid 8192 x 256 thr (2 rows/block). ~8 independent 512B val reads per row.
// Exact fallback (never expected): cnt>CAP -> scan all (n,k) of the batch;
// every entry of a flagged segment had its vector written, so this is exact.
__global__ __launch_bounds__(256) void k_gather(
        const int* __restrict__ fps, const unsigned int* __restrict__ cnt,
        const int* __restrict__ list, const float* __restrict__ val,
        const int* __restrict__ gidx, float* __restrict__ gdil) {
    __shared__ int ent[2][CAP];
    int t = threadIdx.x;
    int half = t >> 7, ch = t & 127;
    int row = blockIdx.x * 2 + half;
    int bb = row >> 12;
    int sg = fps[row];
    unsigned int m = cnt[bb * Ns + sg];
    int mm = (int)(m < (unsigned)CAP ? m : (unsigned)CAP);
    if (ch < mm) ent[half][ch] = list[((size_t)bb * Ns + sg) * CAP + ch];
    __syncthreads();
    float acc = 0.f;
    if (m <= (unsigned)CAP) {
        #pragma unroll 4
        for (int e = 0; e < mm; e++)
            acc = fmaxf(acc, val[((size_t)bb * NK + ent[half][e]) * 128 + ch]);
    } else {                            // exact fallback, statistically never
        const int* gj = gidx + (size_t)bb * NK;
        for (int e = 0; e < NK; e++)
            if (gj[e] == sg)
                acc = fmaxf(acc, val[((size_t)bb * NK + e) * 128 + ch]);
    }
    gdil[(size_t)row * 128 + ch] = acc;
}

// ---- GEMM1 (bf16 MFMA): h1(row,128) = [gx|gdil](row,256) @ w1^T + b1 ----
// Grid 512 (2 blocks/CU): row-tile rt=bid>>1 (BM=64), col-half c0g=(bid&1)*64.
// A is now fully dense (gdil pre-gathered) -- no indirection.
__global__ __launch_bounds__(512) void k_gemm1(
        const float* __restrict__ gx, const float* __restrict__ gdil,
        const float* __restrict__ w1, const float* __restrict__ b1,
        float* __restrict__ h1, float* __restrict__ part) {
    __shared__ __align__(16) unsigned short A_lds[64][72];
    __shared__ __align__(16) unsigned short B_lds[64][72];
    __shared__ float reds[8][32], redq[8][32];
    int t = threadIdx.x;
    int rt = blockIdx.x >> 1;
    int m0 = rt * 64;
    int c0g = (blockIdx.x & 1) * 64;
    int w = t >> 6, l = t & 63;
    int r0 = (w >> 1) * 16, c0 = (w & 1) * 32;
    int lr = l & 15, lk = (l >> 4) * 8;
    f32x4 acc[2] = {};
    for (int k0 = 0; k0 < 256; k0 += 64) {
        __syncthreads();
        #pragma unroll
        for (int i = 0; i < 2; i++) {           // A: 64x64 f32 -> bf16
            int q = t + i * 512;
            int row = q >> 4, kq = (q & 15) * 4;
            int k = k0 + kq;
            float4 v;
            if (k0 < 128) v = *(const float4*)(gx + (size_t)(m0 + row) * 128 + k);
            else          v = *(const float4*)(gdil + (size_t)(m0 + row) * 128 + (k - 128));
            ushort4 o{f2bf(v.x), f2bf(v.y), f2bf(v.z), f2bf(v.w)};
            *(ushort4*)&A_lds[row][kq] = o;
        }
        #pragma unroll
        for (int i = 0; i < 2; i++) {           // B: 64 cols x 64 k from w1
            int q = t + i * 512;
            int col = q >> 4, kq = (q & 15) * 4;
            float4 v = *(const float4*)(w1 + (size_t)(c0g + col) * 256 + k0 + kq);
            ushort4 o{f2bf(v.x), f2bf(v.y), f2bf(v.z), f2bf(v.w)};
            *(ushort4*)&B_lds[col][kq] = o;
        }
        __syncthreads();
        #pragma unroll
        for (int ks = 0; ks < 2; ks++) {
            short8 a = *(const short8*)&A_lds[r0 + lr][ks * 32 + lk];
            #pragma unroll
            for (int cb = 0; cb < 2; cb++) {
                short8 b = *(const short8*)&B_lds[c0 + cb * 16 + lr][ks * 32 + lk];
                acc[cb] = __builtin_amdgcn_mfma_f32_16x16x32_bf16(a, b, acc[cb], 0, 0, 0);
            }
        }
    }
    int orow = m0 + r0 + (l >> 4) * 4;
    #pragma unroll
    for (int cb = 0; cb < 2; cb++) {
        int lc = c0 + cb * 16 + lr;             // local col 0..63
        int col = c0g + lc;
        float bias = b1[col];
        float sv = 0.f, qv = 0.f;
        #pragma unroll
        for (int r = 0; r < 4; r++) {
            float o = acc[cb][r] + bias;
            h1[(size_t)(orow + r) * 128 + col] = o;
            sv += o; qv += o * o;
        }
        sv += __shfl_xor(sv, 16, 64); sv += __shfl_xor(sv, 32, 64);
        qv += __shfl_xor(qv, 16, 64); qv += __shfl_xor(qv, 32, 64);
        if (l < 16) { reds[w][cb * 16 + l] = sv; redq[w][cb * 16 + l] = qv; }
    }
    __syncthreads();
    if (t < 64) {           // cols 0..31 in waves {0,2,4,6}, 32..63 in {1,3,5,7}
        int par = t >> 5, o = t & 31;
        float s = reds[par][o] + reds[par + 2][o] + reds[par + 4][o] + reds[par + 6][o];
        float q = redq[par][o] + redq[par + 2][o] + redq[par + 4][o] + redq[par + 6][o];
        part[rt * 128 + c0g + t] = s;
        part[QOFF + rt * 128 + c0g + t] = q;
    }
}

// ---- GEMM2 (bf16 MFMA): inline BN1 finalize, h2 = relu(bn1(h1)) @ w2^T + b2 ----
__global__ __launch_bounds__(512) void k_gemm2(
        const float* __restrict__ h1, const float* __restrict__ part1,
        const float* __restrict__ g1, const float* __restrict__ be1,
        const float* __restrict__ w2, const float* __restrict__ b2,
        float* __restrict__ h2, float* __restrict__ part2) {
    __shared__ __align__(16) unsigned short A_lds[64][72];
    __shared__ __align__(16) unsigned short B_lds[64][72];
    __shared__ float reds[8][32], redq[8][32];
    __shared__ float ssc[128], ssh[128], tmp[256];
    int t = threadIdx.x;
    int rt = blockIdx.x >> 1;
    int m0 = rt * 64;
    int c0g = (blockIdx.x & 1) * 64;
    if (t < 256) {          // inline finalize of BN1 stats (parallel in all blocks)
        int ch = t & 127;
        const float* src = part1 + (t >> 7) * QOFF + ch;
        float a = 0.f;
        #pragma unroll 8
        for (int j = 0; j < NPART; j++) a += src[j * 128];
        tmp[t] = a;
    }
    __syncthreads();
    if (t < 128) {
        float mean = tmp[t] * (1.0f / 16384.0f);
        float var = tmp[t + 128] * (1.0f / 16384.0f) - mean * mean;
        float sc = g1[t] * rsqrtf(var + EPS);
        ssc[t] = sc;
        ssh[t] = be1[t] - mean * sc;
    }
    __syncthreads();
    int w = t >> 6, l = t & 63;
    int r0 = (w >> 1) * 16, c0 = (w & 1) * 32;
    int lr = l & 15, lk = (l >> 4) * 8;
    f32x4 acc[2] = {};
    for (int k0 = 0; k0 < 128; k0 += 64) {
        __syncthreads();
        #pragma unroll
        for (int i = 0; i < 2; i++) {           // A: relu(bn1(h1)) -> bf16
            int q = t + i * 512;
            int row = q >> 4, kq = (q & 15) * 4;
            int k = k0 + kq;
            float4 v = *(const float4*)(h1 + (size_t)(m0 + row) * 128 + k);
            float a0 = fmaxf(0.f, fmaf(v.x, ssc[k + 0], ssh[k + 0]));
            float a1 = fmaxf(0.f, fmaf(v.y, ssc[k + 1], ssh[k + 1]));
            float a2 = fmaxf(0.f, fmaf(v.z, ssc[k + 2], ssh[k + 2]));
            float a3 = fmaxf(0.f, fmaf(v.w, ssc[k + 3], ssh[k + 3]));
            ushort4 o{f2bf(a0), f2bf(a1), f2bf(a2), f2bf(a3)};
            *(ushort4*)&A_lds[row][kq] = o;
        }
        #pragma unroll
        for (int i = 0; i < 2; i++) {           // B: 64 cols x 64 k from w2
            int q = t + i * 512;
            int col = q >> 4, kq = (q & 15) * 4;
            float4 v = *(const float4*)(w2 + (size_t)(c0g + col) * 128 + k0 + kq);
            ushort4 o{f2bf(v.x), f2bf(v.y), f2bf(v.z), f2bf(v.w)};
            *(ushort4*)&B_lds[col][kq] = o;
        }
        __syncthreads();
        #pragma unroll
        for (int ks = 0; ks < 2; ks++) {
            short8 a = *(const short8*)&A_lds[r0 + lr][ks * 32 + lk];
            #pragma unroll
            for (int cb = 0; cb < 2; cb++) {
                short8 b = *(const short8*)&B_lds[c0 + cb * 16 + lr][ks * 32 + lk];
                acc[cb] = __builtin_amdgcn_mfma_f32_16x16x32_bf16(a, b, acc[cb], 0, 0, 0);
            }
        }
    }
    int orow = m0 + r0 + (l >> 4) * 4;
    #pragma unroll
    for (int cb = 0; cb < 2; cb++) {
        int lc = c0 + cb * 16 + lr;
        int col = c0g + lc;
        float bias = b2[col];
        float sv = 0.f, qv = 0.f;
        #pragma unroll
        for (int r = 0; r < 4; r++) {
            float o = acc[cb][r] + bias;
            h2[(size_t)(orow + r) * 128 + col] = o;
            sv += o; qv += o * o;
        }
        sv += __shfl_xor(sv, 16, 64); sv += __shfl_xor(sv, 32, 64);
        qv += __shfl_xor(qv, 16, 64); qv += __shfl_xor(qv, 32, 64);
        if (l < 16) { reds[w][cb * 16 + l] = sv; redq[w][cb * 16 + l] = qv; }
    }
    __syncthreads();
    if (t < 64) {
        int par = t >> 5, o = t & 31;
        float s = reds[par][o] + reds[par + 2][o] + reds[par + 4][o] + reds[par + 6][o];
        float q = redq[par][o] + redq[par + 2][o] + redq[par + 4][o] + redq[par + 6][o];
        part2[rt * 128 + c0g + t] = s;
        part2[QOFF + rt * 128 + c0g + t] = q;
    }
}

// ---- final: inline BN2 finalize, bn2+relu on h2, transpose to (b, c, n) ----
__global__ __launch_bounds__(512) void k_out(const float* __restrict__ h2,
                                             const float* __restrict__ part2,
                                             const float* __restrict__ g2,
                                             const float* __restrict__ be2,
                                             float* __restrict__ out) {
    __shared__ float tile[64][129];
    __shared__ float lsc[128], lsh[128], tmp[256];
    int t = threadIdx.x;
    int bb = blockIdx.y, n0 = blockIdx.x * 64;
    if (t < 256) {
        int ch = t & 127;
        const float* src = part2 + (t >> 7) * QOFF + ch;
        float a = 0.f;
        #pragma unroll 8
        for (int j = 0; j < NPART; j++) a += src[j * 128];
        tmp[t] = a;
    }
    __syncthreads();
    if (t < 128) {
        float mean = tmp[t] * (1.0f / 16384.0f);
        float var = tmp[t + 128] * (1.0f / 16384.0f) - mean * mean;
        float sc = g2[t] * rsqrtf(var + EPS);
        lsc[t] = sc;
        lsh[t] = be2[t] - mean * sc;
    }
    #pragma unroll
    for (int i = 0; i < 4; i++) {               // load 64 rows x 128 ch
        int fq = t + i * 512;
        int row = fq >> 5;
        int c4 = (fq & 31) * 4;
        float4 v = *(const float4*)(h2 + ((size_t)(bb * Nn + n0 + row)) * 128 + c4);
        tile[row][c4 + 0] = v.x; tile[row][c4 + 1] = v.y;
        tile[row][c4 + 2] = v.z; tile[row][c4 + 3] = v.w;
    }
    __syncthreads();
    int j = t & 63, og = t >> 6;                // lanes sweep n for coalesced writes
    #pragma unroll
    for (int o = og; o < 128; o += 8) {
        float v = fmaxf(0.f, fmaf(tile[j][o], lsc[o], lsh[o]));
        out[((size_t)(bb * 128 + o)) * Nn + n0 + j] = v;
    }
}

extern "C" void kernel_launch(void* const* d_in, const int* in_sizes, int n_in,
                              void* d_out, int out_size, void* d_ws, size_t ws_size,
                              hipStream_t stream) {
    const float* x    = (const float*)d_in[0];
    const int*   gidx = (const int*)d_in[1];
    const int*   fps  = (const int*)d_in[2];
    // d_in[3] = N (16384), known statically
    const float* w1   = (const float*)d_in[4];
    const float* b1   = (const float*)d_in[5];
    const float* g1   = (const float*)d_in[6];
    const float* be1  = (const float*)d_in[7];
    const float* w2   = (const float*)d_in[8];
    const float* b2   = (const float*)d_in[9];
    const float* g2   = (const float*)d_in[10];
    const float* be2  = (const float*)d_in[11];
    float* out = (float*)d_out;

    char* ws = (char*)d_ws;
    float* gx          = (float*)(ws + OFF_GX);
    float* gdil        = (float*)(ws + OFF_GDIL);
    float* h1          = (float*)(ws + OFF_H1);
    float* h2          = (float*)(ws + OFF_H2);
    float* part1       = (float*)(ws + OFF_P1);
    float* part2       = (float*)(ws + OFF_P2);
    int* flags         = (int*)(ws + OFF_FLAG);
    unsigned int* cnt  = (unsigned int*)(ws + OFF_CNT);
    int* list          = (int*)(ws + OFF_LIST);
    float* val         = (float*)(ws + OFF_VAL);

    k_prep<<<256, 256, 0, stream>>>(fps, flags, cnt);
    k_scatter<<<dim3(Nn, Bb), 256, 0, stream>>>(x, gidx, flags, fps, cnt, list, gx, val);
    k_gather<<<ROWS / 2, 256, 0, stream>>>(fps, cnt, list, val, gidx, gdil);
    k_gemm1<<<ROWS / 32, 512, 0, stream>>>(gx, gdil, w1, b1, h1, part1);
    k_gemm2<<<ROWS / 32, 512, 0, stream>>>(h1, part1, g1, be1, w2, b2, h2, part2);
    k_out<<<dim3(Nn / 64, Bb), 512, 0, stream>>>(h2, part2, g2, be2, out);
}

// Round 18
// 121.072 us; speedup vs baseline: 1.2387x; 1.2387x over previous
//
#include <hip/hip_runtime.h>

// Problem dims (fixed by setup_inputs)
constexpr int Bb = 4, Cc = 128, Nn = 4096, Kk = 32, Ns = 16384;
constexpr int ROWS = Bb * Nn;   // 16384 (b*n) rows
constexpr int NK = Nn * Kk;     // 131072 floats per channel slab
constexpr int NPART = 256;      // stats-partial sets (= row-tiles)
constexpr int QOFF = NPART * 128;
constexpr float EPS = 1e-5f;

typedef __attribute__((ext_vector_type(8))) short short8;
typedef __attribute__((ext_vector_type(4))) float f32x4;

__device__ __forceinline__ unsigned short f2bf(float f) {   // RNE f32->bf16
    unsigned int u = __float_as_uint(f);
    unsigned int r = u + 0x7FFFu + ((u >> 16) & 1u);
    return (unsigned short)(r >> 16);
}

// ---- workspace layout (bytes) ----
constexpr size_t SZ_SEG   = (size_t)Bb * Ns * Cc * 4;   // 32 MB scatter-max targets
constexpr size_t OFF_SEG  = 0;
constexpr size_t SZ_GX    = (size_t)ROWS * Cc * 4;      // 8 MB
constexpr size_t OFF_GX   = OFF_SEG + SZ_SEG;
constexpr size_t OFF_H1   = OFF_GX + SZ_GX;
constexpr size_t OFF_H2   = OFF_H1 + SZ_GX;
constexpr size_t SZ_PART  = (size_t)NPART * 128 * 2 * 4;
constexpr size_t OFF_P1   = OFF_H2 + SZ_GX;
constexpr size_t OFF_P2   = OFF_P1 + SZ_PART;
constexpr size_t OFF_FLAG = OFF_P2 + SZ_PART;           // 256 KB int32 verified flags

// ---- prep: zero gathered seg rows + write verified flags (no clearing needed) ----
// flags[bb*Ns+fi] = i (claiming gather-row). Garbage entry j validates only if
// fps[j]==fi with j in batch bb -- which itself proves fi is in the set.
__global__ __launch_bounds__(256) void k_prep(const int* __restrict__ fps,
                                              float4* __restrict__ seg4,
                                              int* __restrict__ flags) {
    int i = blockIdx.x * 32 + (threadIdx.x >> 3);   // gather-row index 0..16383
    int lane = threadIdx.x & 7;
    int bb = i >> 12;
    int fi = fps[i];
    if (lane == 0) flags[bb * Ns + fi] = i;
    float4 z{0.f, 0.f, 0.f, 0.f};
    size_t base = ((size_t)bb * Ns + fi) * 32 + lane;
    seg4[base + 0] = z; seg4[base + 8] = z;
    seg4[base + 16] = z; seg4[base + 24] = z;
}

// ---- fused: local max over k + row-contiguous atomic scatter ----
// grid (4096, 4), 256 threads. Block = one (b, n): 128 channels x 32 k.
// Phase 1: coalesced x loads, 3-shuffle max; park ONLY flagged k-columns in
//          LDS (fmask; ~22% flagged). Phase 2: compacted flagged-k list; per
//          k, 128 consecutive lanes sweep one seg row -> 256B-contiguous
//          atomic runs (R10/R11: line-packing is the atomic cost driver).
__global__ __launch_bounds__(256) void k_scatter(
        const float* __restrict__ x, const int* __restrict__ gidx,
        const int* __restrict__ flags, const int* __restrict__ fps,
        float* __restrict__ gx, unsigned int* __restrict__ seg) {
    int nn = blockIdx.x, bb = blockIdx.y;
    int t = threadIdx.x;
    __shared__ float tile[128][33];
    __shared__ float gbuf[128];
    __shared__ unsigned int srow[32];
    __shared__ int klist[32];
    __shared__ int nflag;
    __shared__ unsigned int fmask;

    if (t == 0) { nflag = 0; fmask = 0u; }
    __syncthreads();
    if (t < 32) {
        int idxv = gidx[((bb * Nn + nn) << 5) + t];
        srow[t] = (unsigned int)(bb * Ns + idxv) * 128u;
        int fl = flags[bb * Ns + idxv];
        int j = fl & 16383;
        if (((j >> 12) == bb) && (fps[j] == idxv)) {
            int pos = atomicAdd(&nflag, 1);
            klist[pos] = t;
            atomicOr(&fmask, 1u << t);
        }
    }

    int k4 = (t & 7) * 4;
    int cq = t >> 3;                    // 0..31
    const float* xb = x + (size_t)bb * Cc * NK + (size_t)nn * Kk;
    float4 v[4];
    #pragma unroll
    for (int p = 0; p < 4; p++)
        v[p] = *(const float4*)(xb + (size_t)(cq + p * 32) * NK + k4);

    __syncthreads();                    // fmask/srow/klist ready
    unsigned int mask = fmask;
    bool f0 = (mask >> (k4 + 0)) & 1, f1 = (mask >> (k4 + 1)) & 1;
    bool f2 = (mask >> (k4 + 2)) & 1, f3 = (mask >> (k4 + 3)) & 1;

    #pragma unroll
    for (int p = 0; p < 4; p++) {
        int ch = cq + p * 32;
        float4 w = v[p];
        float m = fmaxf(fmaxf(w.x, w.y), fmaxf(w.z, w.w));
        m = fmaxf(m, __shfl_xor(m, 1, 64));
        m = fmaxf(m, __shfl_xor(m, 2, 64));
        m = fmaxf(m, __shfl_xor(m, 4, 64));
        if ((t & 7) == 0) gbuf[ch] = m;
        if (f0) tile[ch][k4 + 0] = w.x;
        if (f1) tile[ch][k4 + 1] = w.y;
        if (f2) tile[ch][k4 + 2] = w.z;
        if (f3) tile[ch][k4 + 3] = w.w;
    }
    __syncthreads();

    if (t < 128) gx[((size_t)(bb * Nn + nn)) * 128 + t] = gbuf[t];

    int nf = nflag;
    int ch = t & 127, rep = t >> 7;     // two half-blocks process 2 k's/iter
    for (int it = rep; it < nf; it += 2) {
        int k = klist[it];
        float val = tile[ch][k];
        if (val > 0.f) atomicMax(seg + srow[k] + ch, __float_as_uint(val));
    }
}

// ---- GEMM1 (bf16 MFMA): h1(row,128) = A(row,256) @ w1^T + b1 ; BN partials ----
// Grid 512 (2 blocks/CU): row-tile rt=bid>>1 (BM=64), col-half c0g=(bid&1)*64.
// 8 waves: wave w -> rows (w>>1)*16, local cols (w&1)*32 (2x 16x16 frags).
// The two col-halves of a row-tile write disjoint halves of part set rt.
__global__ __launch_bounds__(512) void k_gemm1(
        const float* __restrict__ gx, const float* __restrict__ segf,
        const int* __restrict__ fps, const float* __restrict__ w1,
        const float* __restrict__ b1, float* __restrict__ h1,
        float* __restrict__ part) {
    __shared__ __align__(16) unsigned short A_lds[64][72];
    __shared__ __align__(16) unsigned short B_lds[64][72];
    __shared__ float reds[8][32], redq[8][32];
    __shared__ int rowbase[64];
    int t = threadIdx.x;
    int rt = blockIdx.x >> 1;
    int m0 = rt * 64;
    int c0g = (blockIdx.x & 1) * 64;
    if (t < 64) rowbase[t] = (((m0 + t) >> 12) * Ns + fps[m0 + t]) * 128;
    int w = t >> 6, l = t & 63;
    int r0 = (w >> 1) * 16, c0 = (w & 1) * 32;
    int lr = l & 15, lk = (l >> 4) * 8;
    f32x4 acc[2] = {};
    for (int k0 = 0; k0 < 256; k0 += 64) {
        __syncthreads();
        #pragma unroll
        for (int i = 0; i < 2; i++) {           // A: 64x64 f32 -> bf16
            int q = t + i * 512;
            int row = q >> 4, kq = (q & 15) * 4;
            int k = k0 + kq;
            float4 v;
            if (k0 < 128) v = *(const float4*)(gx + (size_t)(m0 + row) * 128 + k);
            else          v = *(const float4*)(segf + rowbase[row] + (k - 128));
            ushort4 o{f2bf(v.x), f2bf(v.y), f2bf(v.z), f2bf(v.w)};
            *(ushort4*)&A_lds[row][kq] = o;
        }
        #pragma unroll
        for (int i = 0; i < 2; i++) {           // B: 64 cols x 64 k from w1
            int q = t + i * 512;
            int col = q >> 4, kq = (q & 15) * 4;
            float4 v = *(const float4*)(w1 + (size_t)(c0g + col) * 256 + k0 + kq);
            ushort4 o{f2bf(v.x), f2bf(v.y), f2bf(v.z), f2bf(v.w)};
            *(ushort4*)&B_lds[col][kq] = o;
        }
        __syncthreads();
        #pragma unroll
        for (int ks = 0; ks < 2; ks++) {
            short8 a = *(const short8*)&A_lds[r0 + lr][ks * 32 + lk];
            #pragma unroll
            for (int cb = 0; cb < 2; cb++) {
                short8 b = *(const short8*)&B_lds[c0 + cb * 16 + lr][ks * 32 + lk];
                acc[cb] = __builtin_amdgcn_mfma_f32_16x16x32_bf16(a, b, acc[cb], 0, 0, 0);
            }
        }
    }
    int orow = m0 + r0 + (l >> 4) * 4;
    #pragma unroll
    for (int cb = 0; cb < 2; cb++) {
        int lc = c0 + cb * 16 + lr;             // local col 0..63
        int col = c0g + lc;
        float bias = b1[col];
        float sv = 0.f, qv = 0.f;
        #pragma unroll
        for (int r = 0; r < 4; r++) {
            float o = acc[cb][r] + bias;
            h1[(size_t)(orow + r) * 128 + col] = o;
            sv += o; qv += o * o;
        }
        sv += __shfl_xor(sv, 16, 64); sv += __shfl_xor(sv, 32, 64);
        qv += __shfl_xor(qv, 16, 64); qv += __shfl_xor(qv, 32, 64);
        if (l < 16) { reds[w][cb * 16 + l] = sv; redq[w][cb * 16 + l] = qv; }
    }
    __syncthreads();
    if (t < 64) {           // cols 0..31 in waves {0,2,4,6}, 32..63 in {1,3,5,7}
        int par = t >> 5, o = t & 31;
        float s = reds[par][o] + reds[par + 2][o] + reds[par + 4][o] + reds[par + 6][o];
        float q = redq[par][o] + redq[par + 2][o] + redq[par + 4][o] + redq[par + 6][o];
        part[rt * 128 + c0g + t] = s;
        part[QOFF + rt * 128 + c0g + t] = q;
    }
}

// ---- GEMM2 (bf16 MFMA): inline BN1 finalize, h2 = relu(bn1(h1)) @ w2^T + b2 ----
__global__ __launch_bounds__(512) void k_gemm2(
        const float* __restrict__ h1, const float* __restrict__ part1,
        const float* __restrict__ g1, const float* __restrict__ be1,
        const float* __restrict__ w2, const float* __restrict__ b2,
        float* __restrict__ h2, float* __restrict__ part2) {
    __shared__ __align__(16) unsigned short A_lds[64][72];
    __shared__ __align__(16) unsigned short B_lds[64][72];
    __shared__ float reds[8][32], redq[8][32];
    __shared__ float ssc[128], ssh[128], tmp[256];
    int t = threadIdx.x;
    int rt = blockIdx.x >> 1;
    int m0 = rt * 64;
    int c0g = (blockIdx.x & 1) * 64;
    if (t < 256) {          // inline finalize of BN1 stats (parallel in all blocks)
        int ch = t & 127;
        const float* src = part1 + (t >> 7) * QOFF + ch;
        float a = 0.f;
        #pragma unroll 8
        for (int j = 0; j < NPART; j++) a += src[j * 128];
        tmp[t] = a;
    }
    __syncthreads();
    if (t < 128) {
        float mean = tmp[t] * (1.0f / 16384.0f);
        float var = tmp[t + 128] * (1.0f / 16384.0f) - mean * mean;
        float sc = g1[t] * rsqrtf(var + EPS);
        ssc[t] = sc;
        ssh[t] = be1[t] - mean * sc;
    }
    __syncthreads();
    int w = t >> 6, l = t & 63;
    int r0 = (w >> 1) * 16, c0 = (w & 1) * 32;
    int lr = l & 15, lk = (l >> 4) * 8;
    f32x4 acc[2] = {};
    for (int k0 = 0; k0 < 128; k0 += 64) {
        __syncthreads();
        #pragma unroll
        for (int i = 0; i < 2; i++) {           // A: relu(bn1(h1)) -> bf16
            int q = t + i * 512;
            int row = q >> 4, kq = (q & 15) * 4;
            int k = k0 + kq;
            float4 v = *(const float4*)(h1 + (size_t)(m0 + row) * 128 + k);
            float a0 = fmaxf(0.f, fmaf(v.x, ssc[k + 0], ssh[k + 0]));
            float a1 = fmaxf(0.f, fmaf(v.y, ssc[k + 1], ssh[k + 1]));
            float a2 = fmaxf(0.f, fmaf(v.z, ssc[k + 2], ssh[k + 2]));
            float a3 = fmaxf(0.f, fmaf(v.w, ssc[k + 3], ssh[k + 3]));
            ushort4 o{f2bf(a0), f2bf(a1), f2bf(a2), f2bf(a3)};
            *(ushort4*)&A_lds[row][kq] = o;
        }
        #pragma unroll
        for (int i = 0; i < 2; i++) {           // B: 64 cols x 64 k from w2
            int q = t + i * 512;
            int col = q >> 4, kq = (q & 15) * 4;
            float4 v = *(const float4*)(w2 + (size_t)(c0g + col) * 128 + k0 + kq);
            ushort4 o{f2bf(v.x), f2bf(v.y), f2bf(v.z), f2bf(v.w)};
            *(ushort4*)&B_lds[col][kq] = o;
        }
        __syncthreads();
        #pragma unroll
        for (int ks = 0; ks < 2; ks++) {
            short8 a = *(const short8*)&A_lds[r0 + lr][ks * 32 + lk];
            #pragma unroll
            for (int cb = 0; cb < 2; cb++) {
                short8 b = *(const short8*)&B_lds[c0 + cb * 16 + lr][ks * 32 + lk];
                acc[cb] = __builtin_amdgcn_mfma_f32_16x16x32_bf16(a, b, acc[cb], 0, 0, 0);
            }
        }
    }
    int orow = m0 + r0 + (l >> 4) * 4;
    #pragma unroll
    for (int cb = 0; cb < 2; cb++) {
        int lc = c0 + cb * 16 + lr;
        int col = c0g + lc;
        float bias = b2[col];
        float sv = 0.f, qv = 0.f;
        #pragma unroll
        for (int r = 0; r < 4; r++) {
            float o = acc[cb][r] + bias;
            h2[(size_t)(orow + r) * 128 + col] = o;
            sv += o; qv += o * o;
        }
        sv += __shfl_xor(sv, 16, 64); sv += __shfl_xor(sv, 32, 64);
        qv += __shfl_xor(qv, 16, 64); qv += __shfl_xor(qv, 32, 64);
        if (l < 16) { reds[w][cb * 16 + l] = sv; redq[w][cb * 16 + l] = qv; }
    }
    __syncthreads();
    if (t < 64) {
        int par = t >> 5, o = t & 31;
        float s = reds[par][o] + reds[par + 2][o] + reds[par + 4][o] + reds[par + 6][o];
        float q = redq[par][o] + redq[par + 2][o] + redq[par + 4][o] + redq[par + 6][o];
        part2[rt * 128 + c0g + t] = s;
        part2[QOFF + rt * 128 + c0g + t] = q;
    }
}

// ---- final: inline BN2 finalize, bn2+relu on h2, transpose to (b, c, n) ----
__global__ __launch_bounds__(512) void k_out(const float* __restrict__ h2,
                                             const float* __restrict__ part2,
                                             const float* __restrict__ g2,
                                             const float* __restrict__ be2,
                                             float* __restrict__ out) {
    __shared__ float tile[64][129];
    __shared__ float lsc[128], lsh[128], tmp[256];
    int t = threadIdx.x;
    int bb = blockIdx.y, n0 = blockIdx.x * 64;
    if (t < 256) {
        int ch = t & 127;
        const float* src = part2 + (t >> 7) * QOFF + ch;
        float a = 0.f;
        #pragma unroll 8
        for (int j = 0; j < NPART; j++) a += src[j * 128];
        tmp[t] = a;
    }
    __syncthreads();
    if (t < 128) {
        float mean = tmp[t] * (1.0f / 16384.0f);
        float var = tmp[t + 128] * (1.0f / 16384.0f) - mean * mean;
        float sc = g2[t] * rsqrtf(var + EPS);
        lsc[t] = sc;
        lsh[t] = be2[t] - mean * sc;
    }
    #pragma unroll
    for (int i = 0; i < 4; i++) {               // load 64 rows x 128 ch
        int fq = t + i * 512;
        int row = fq >> 5;
        int c4 = (fq & 31) * 4;
        float4 v = *(const float4*)(h2 + ((size_t)(bb * Nn + n0 + row)) * 128 + c4);
        tile[row][c4 + 0] = v.x; tile[row][c4 + 1] = v.y;
        tile[row][c4 + 2] = v.z; tile[row][c4 + 3] = v.w;
    }
    __syncthreads();
    int j = t & 63, og = t >> 6;                // lanes sweep n for coalesced writes
    #pragma unroll
    for (int o = og; o < 128; o += 8) {
        float v = fmaxf(0.f, fmaf(tile[j][o], lsc[o], lsh[o]));
        out[((size_t)(bb * 128 + o)) * Nn + n0 + j] = v;
    }
}

extern "C" void kernel_launch(void* const* d_in, const int* in_sizes, int n_in,
                              void* d_out, int out_size, void* d_ws, size_t ws_size,
                              hipStream_t stream) {
    const float* x    = (const float*)d_in[0];
    const int*   gidx = (const int*)d_in[1];
    const int*   fps  = (const int*)d_in[2];
    // d_in[3] = N (16384), known statically
    const float* w1   = (const float*)d_in[4];
    const float* b1   = (const float*)d_in[5];
    const float* g1   = (const float*)d_in[6];
    const float* be1  = (const float*)d_in[7];
    const float* w2   = (const float*)d_in[8];
    const float* b2   = (const float*)d_in[9];
    const float* g2   = (const float*)d_in[10];
    const float* be2  = (const float*)d_in[11];
    float* out = (float*)d_out;

    char* ws = (char*)d_ws;
    unsigned int* seg  = (unsigned int*)(ws + OFF_SEG);
    float* segf        = (float*)(ws + OFF_SEG);
    float4* seg4       = (float4*)(ws + OFF_SEG);
    float* gx          = (float*)(ws + OFF_GX);
    float* h1          = (float*)(ws + OFF_H1);
    float* h2          = (float*)(ws + OFF_H2);
    float* part1       = (float*)(ws + OFF_P1);
    float* part2       = (float*)(ws + OFF_P2);
    int* flags         = (int*)(ws + OFF_FLAG);

    k_prep<<<ROWS / 32, 256, 0, stream>>>(fps, seg4, flags);
    k_scatter<<<dim3(Nn, Bb), 256, 0, stream>>>(x, gidx, flags, fps, gx, seg);
    k_gemm1<<<ROWS / 32, 512, 0, stream>>>(gx, segf, fps, w1, b1, h1, part1);
    k_gemm2<<<ROWS / 32, 512, 0, stream>>>(h1, part1, g1, be1, w2, b2, h2, part2);
    k_out<<<dim3(Nn / 64, Bb), 512, 0, stream>>>(h2, part2, g2, be2, out);
}